// Round 8
// baseline (201.005 us; speedup 1.0000x reference)
//
#include <hip/hip_runtime.h>
#include <hip/hip_bf16.h>

typedef __attribute__((ext_vector_type(4))) float f32x4;
typedef __attribute__((ext_vector_type(8))) short short8;
typedef __attribute__((ext_vector_type(4))) unsigned short us4;
typedef __attribute__((ext_vector_type(4))) unsigned int u32x4;

#define BH_ 128
#define N_ 4096
#define LOG2E 1.4426950408889634f
#define NORML (0.35355339059327373f * LOG2E)  // d^-0.25 * log2(e) folded into P
#define DIAGL (0.0625f * LOG2E)               // 0.5*d^-0.5 * log2(e)
#define EPSF 1e-4f

#if __has_builtin(__builtin_amdgcn_exp2f)
#define EXP2F(x) __builtin_amdgcn_exp2f(x)
#else
#define EXP2F(x) exp2f(x)
#endif

// LDS-only barrier: orders ds_write/ds_read across waves WITHOUT draining
// vmcnt — in-flight global prefetch loads survive the barrier (T4).
#define BARRIER_LGKM() asm volatile("s_waitcnt lgkmcnt(0)\ns_barrier" ::: "memory")

static __device__ __forceinline__ unsigned short f2bf(float f) {
  return __bfloat16_as_ushort(__float2bfloat16(f));  // RNE, HW cvt
}
static __device__ __forceinline__ float bf2f(unsigned short s) {
  return __uint_as_float(((unsigned int)s) << 16);
}
static __device__ __forceinline__ us4 cvt4(f32x4 x) {
  us4 r;
  r[0] = f2bf(x[0]); r[1] = f2bf(x[1]); r[2] = f2bf(x[2]); r[3] = f2bf(x[3]);
  return r;
}
static __device__ __forceinline__ unsigned int pk2bf(float lo, float hi) {
  unsigned int r;
  asm("v_cvt_pk_bf16_f32 %0, %1, %2" : "=v"(r) : "v"(lo), "v"(hi));
  return r;
}

// m-permutation for qpass GEMM2 (bijective bit shuffle): pos = [b7b6b5|b3b2|b4|b1b0]
static __device__ __forceinline__ int posm(int m) {
  return (m & 0xE0) | ((m & 0xC) << 1) | ((m & 0x10) >> 2) | (m & 3);
}

// ---------------------------------------------------------------------------
// prep: projection -> bf16 with NORML folded (consumed by qpass GEMM1).
// ---------------------------------------------------------------------------
__global__ void perf_prep(const float* __restrict__ proj,
                          unsigned short* __restrict__ projb) {
  int i = blockIdx.x * 256 + threadIdx.x;  // 16384 total
  projb[i] = f2bf(proj[i] * NORML);
}

// ---------------------------------------------------------------------------
// K pass v2 — zero-shuffle GEMM1->GEMM2 handoff (r7 lesson from qpass v4):
// GEMM2 contracts over n; under k-permutation pi(g,j) = (j>=4)*16+g*4+(j&3),
// the w values each lane holds from GEMM1 (w[n=nh1*16+g*4+r][m=mt*16+c]) ARE
// the A-fragment of mfma(A=w, B=V) — sW LDS round-trip deleted. V is staged
// at column slot kslot(n) = ((n>>2)&3)*8 + (n>>4)*4 + (n&3) so its B-frag is
// a plain ds_read_b128 with the same pi ordering. D lands f32x4-along-m ->
// ctxp layout unchanged. sX/sVt double-buffered -> ONE lgkm barrier/tile.
// RULE (r2/r4): __launch_bounds__(256,2); tighter bounds spill.
// ---------------------------------------------------------------------------
__global__ __launch_bounds__(256, 2)
void perf_kpass(const float* __restrict__ kp, const float* __restrict__ vp,
                const float* __restrict__ proj, float* __restrict__ ctxp,
                float* __restrict__ kexpp, float* __restrict__ vsump,
                unsigned int* __restrict__ gmaxb, int nchunk) {
  const int bh = blockIdx.x & (BH_ - 1);
  const int chunk = blockIdx.x >> 7;
  const int chunkrows = N_ / nchunk;
  const int tiles = chunkrows >> 5;
  const int t = threadIdx.x;
  const int wid = t >> 6;
  const int lane = t & 63;
  const int g = lane >> 4;
  const int c = lane & 15;

  __shared__ __align__(16) unsigned short sX[2][32][72];
  __shared__ __align__(16) unsigned short sVt[2][64][40];
  __shared__ float sDiag[2][32];
  __shared__ float sVsum[64];
  __shared__ float sGm[4];

  short8 pfrag[4][2];
#pragma unroll
  for (int mt = 0; mt < 4; ++mt)
#pragma unroll
    for (int kk = 0; kk < 2; ++kk) {
      const float* src = proj + (wid * 64 + mt * 16 + c) * 64 + kk * 32 + g * 8;
      short8 v;
#pragma unroll
      for (int j = 0; j < 8; ++j) v[j] = (short)f2bf(src[j] * NORML);
      pfrag[mt][kk] = v;
    }

  f32x4 ctx[4][4];
#pragma unroll
  for (int i = 0; i < 4; ++i)
#pragma unroll
    for (int j = 0; j < 4; ++j) ctx[i][j] = (f32x4){0.f, 0.f, 0.f, 0.f};

  float kexpreg[4] = {0.f, 0.f, 0.f, 0.f};
  float vsum0 = 0.f, vsum1 = 0.f, vsum2 = 0.f, vsum3 = 0.f;
  float gm = -1e30f;

  const float* kb0 = kp + ((size_t)bh * N_ + (size_t)chunk * chunkrows) * 64;
  const float* vb0 = vp + ((size_t)bh * N_ + (size_t)chunk * chunkrows) * 64;

  f32x4 kx[2], vx[2];
#pragma unroll
  for (int hh = 0; hh < 2; ++hh) {
    int f = t + hh * 256;
    kx[hh] = *(const f32x4*)(kb0 + (f >> 4) * 64 + (f & 15) * 4);
    vx[hh] = *(const f32x4*)(vb0 + (f >> 4) * 64 + (f & 15) * 4);
  }

  for (int nt = 0; nt < tiles; ++nt) {
    const int buf = nt & 1;
    // ---- stage tile into buf (other buffer than the one being read) ----
#pragma unroll
    for (int hh = 0; hh < 2; ++hh) {
      int f = t + hh * 256;
      int row = f >> 4;
      int c4 = f & 15;
      f32x4 x = kx[hh];
      float ss = x[0] * x[0] + x[1] * x[1] + x[2] * x[2] + x[3] * x[3];
      ss += __shfl_xor(ss, 1);
      ss += __shfl_xor(ss, 2);
      ss += __shfl_xor(ss, 4);
      ss += __shfl_xor(ss, 8);
      if (c4 == 0) sDiag[buf][row] = DIAGL * ss;
      *(us4*)&sX[buf][row][c4 * 4] = cvt4(x);
      f32x4 vv = vx[hh];
      vsum0 += vv[0]; vsum1 += vv[1]; vsum2 += vv[2]; vsum3 += vv[3];
      // V staged at permuted column slot kslot(row) for pi-ordered B-frags
      const int ks = ((row >> 2) & 3) * 8 + (row >> 4) * 4 + (row & 3);
#pragma unroll
      for (int jj = 0; jj < 4; ++jj) {
        int j = (jj + t) & 3;  // rotate to spread banks
        float val = (j == 0) ? vv[0] : (j == 1) ? vv[1] : (j == 2) ? vv[2] : vv[3];
        sVt[buf][c4 * 4 + j][ks] = f2bf(val);
      }
    }
    if (nt + 1 < tiles) {  // prefetch survives the lgkm-only barrier below
      const float* kb = kb0 + (nt + 1) * 2048;
      const float* vb = vb0 + (nt + 1) * 2048;
#pragma unroll
      for (int hh = 0; hh < 2; ++hh) {
        int f = t + hh * 256;
        kx[hh] = *(const f32x4*)(kb + (f >> 4) * 64 + (f & 15) * 4);
        vx[hh] = *(const f32x4*)(vb + (f >> 4) * 64 + (f & 15) * 4);
      }
    }
    BARRIER_LGKM();  // only barrier: staged buf visible; dbuf handles WAR

    // ---- GEMM1: dd[32n x 64m-slice] = X * P^T ----
    short8 afr[2][2];
#pragma unroll
    for (int nh1 = 0; nh1 < 2; ++nh1)
#pragma unroll
      for (int kk = 0; kk < 2; ++kk)
        afr[nh1][kk] = *(const short8*)&sX[buf][nh1 * 16 + c][kk * 32 + g * 8];

    f32x4 acc1[2][4];
#pragma unroll
    for (int i = 0; i < 2; ++i)
#pragma unroll
      for (int j = 0; j < 4; ++j) acc1[i][j] = (f32x4){0.f, 0.f, 0.f, 0.f};
#pragma unroll
    for (int kk = 0; kk < 2; ++kk)
#pragma unroll
      for (int nh1 = 0; nh1 < 2; ++nh1)
#pragma unroll
        for (int mt = 0; mt < 4; ++mt)
          acc1[nh1][mt] = __builtin_amdgcn_mfma_f32_16x16x32_bf16(
              afr[nh1][kk], pfrag[mt][kk], acc1[nh1][mt], 0, 0, 0);

    // ---- w = exp2(dd - diag): packed in pi order = GEMM2 A-frag ----
    short8 wfrag[4];
#pragma unroll
    for (int mt = 0; mt < 4; ++mt) {
#pragma unroll
      for (int nh1 = 0; nh1 < 2; ++nh1)
#pragma unroll
        for (int r = 0; r < 4; ++r) {
          float dd = acc1[nh1][mt][r];
          gm = fmaxf(gm, dd);
          int n = nh1 * 16 + g * 4 + r;
          float w = EXP2F(dd - sDiag[buf][n]);
          unsigned short wb = f2bf(w);
          kexpreg[mt] += bf2f(wb);
          wfrag[mt][nh1 * 4 + r] = (short)wb;
        }
    }

    // ---- GEMM2: ctx[m][e] += mfma(A=wfrag, B=V-frag), k = pi(n) ----
    short8 bvv[4];
#pragma unroll
    for (int et = 0; et < 4; ++et)
      bvv[et] = *(const short8*)&sVt[buf][et * 16 + c][g * 8];
#pragma unroll
    for (int mt2 = 0; mt2 < 4; ++mt2)
#pragma unroll
      for (int et = 0; et < 4; ++et)
        ctx[mt2][et] = __builtin_amdgcn_mfma_f32_16x16x32_bf16(
            wfrag[mt2], bvv[et], ctx[mt2][et], 0, 0, 0);
  }

  // ---- epilogue: partials (layout unchanged: f32x4 along m) ----
#pragma unroll
  for (int mt2 = 0; mt2 < 4; ++mt2)
#pragma unroll
    for (int et = 0; et < 4; ++et) {
      int m0 = wid * 64 + mt2 * 16 + g * 4;
      int e = et * 16 + c;
      size_t base = (((size_t)chunk * BH_ + bh) * 64 + e) * 256 + m0;
      *(f32x4*)(ctxp + base) = ctx[mt2][et];
    }
#pragma unroll
  for (int mt = 0; mt < 4; ++mt) {
    float s = kexpreg[mt];
    s += __shfl_xor(s, 16);
    s += __shfl_xor(s, 32);
    if (lane < 16)
      kexpp[((size_t)chunk * BH_ + bh) * 256 + wid * 64 + mt * 16 + lane] = s;
  }
  if (t < 64) sVsum[t] = 0.f;
  __syncthreads();
  atomicAdd(&sVsum[(t & 15) * 4 + 0], vsum0);
  atomicAdd(&sVsum[(t & 15) * 4 + 1], vsum1);
  atomicAdd(&sVsum[(t & 15) * 4 + 2], vsum2);
  atomicAdd(&sVsum[(t & 15) * 4 + 3], vsum3);
  __syncthreads();
  if (t < 64) vsump[((size_t)chunk * BH_ + bh) * 64 + t] = sVsum[t];

  gm = fmaxf(gm, __shfl_xor(gm, 1));
  gm = fmaxf(gm, __shfl_xor(gm, 2));
  gm = fmaxf(gm, __shfl_xor(gm, 4));
  gm = fmaxf(gm, __shfl_xor(gm, 8));
  gm = fmaxf(gm, __shfl_xor(gm, 16));
  gm = fmaxf(gm, __shfl_xor(gm, 32));
  if (lane == 0) sGm[wid] = gm;
  __syncthreads();
  if (t == 0) {
    float mm = fmaxf(fmaxf(sGm[0], sGm[1]), fmaxf(sGm[2], sGm[3]));
    atomicMax((int*)gmaxb, __float_as_int(mm));  // gmax2 > 0 in practice
  }
}

// ---------------------------------------------------------------------------
// Rescale: CTX -> bf16 [bh][e][pos(m)]; KC -> bf16 hi/lo at pos(m).
// ---------------------------------------------------------------------------
__global__ void perf_rescale(const float* __restrict__ ctxp,
                             const float* __restrict__ kexpp,
                             const float* __restrict__ vsump,
                             unsigned short* __restrict__ ctxt,
                             unsigned short* __restrict__ kchi,
                             unsigned short* __restrict__ kclo,
                             const unsigned int* __restrict__ gmaxb, int nchunk) {
  const int bh = blockIdx.x >> 3;
  const int es = blockIdx.x & 7;
  const int t = threadIdx.x;  // m (source order)
  const int pos = posm(t);
  const float gmax = __uint_as_float(*gmaxb);
  const float s = EXP2F(-gmax);
  if (es == 0) {
    float acc = 0.f;
    for (int cc = 0; cc < nchunk; ++cc)
      acc += kexpp[((size_t)cc * BH_ + bh) * 256 + t];
    float kcv = s * acc + EPSF * (float)N_;
    unsigned short hi = f2bf(kcv);
    kchi[bh * 256 + pos] = hi;
    kclo[bh * 256 + pos] = f2bf(kcv - bf2f(hi));
  }
  for (int e = es * 8; e < es * 8 + 8; ++e) {
    float vs = 0.f;
    for (int cc = 0; cc < nchunk; ++cc)
      vs += vsump[((size_t)cc * BH_ + bh) * 64 + e];
    float a2 = 0.f;
    for (int cc = 0; cc < nchunk; ++cc)
      a2 += ctxp[(((size_t)cc * BH_ + bh) * 64 + e) * 256 + t];
    ctxt[((size_t)bh * 64 + e) * 256 + pos] = f2bf(s * a2 + EPSF * vs);
  }
}

// ---------------------------------------------------------------------------
// Q pass v4 (r7, unchanged) — block stages P/CTX/kc into swizzled LDS once;
// waves independent; swapped GEMM1 + posm() handoff; zero per-tile barriers.
// ---------------------------------------------------------------------------
__global__ __launch_bounds__(256, 2)
void perf_qpass(const float* __restrict__ qp,
                const unsigned short* __restrict__ projb,
                const unsigned short* __restrict__ ctxt,
                const unsigned short* __restrict__ kchi,
                const unsigned short* __restrict__ kclo,
                float* __restrict__ outp) {
  const int bh = blockIdx.x >> 3;
  const int chunk = blockIdx.x & 7;  // 512 rows per block
  const int t = threadIdx.x;
  const int wid = t >> 6;
  const int lane = t & 63;
  const int g = lane >> 4;
  const int c = lane & 15;

  __shared__ __align__(16) unsigned short sP[256 * 64];   // 32KB, swizzled
  __shared__ __align__(16) unsigned short sC[64 * 256];   // 32KB, swizzled
  __shared__ __align__(16) unsigned short sC2[16 * 256];  // 8KB: kc hi/lo tile

  const unsigned short* csrc = ctxt + (size_t)bh * 64 * 256;
  const unsigned short* khib = kchi + bh * 256;
  const unsigned short* klob = kclo + bh * 256;

  const float* qbase = qp + ((size_t)bh * N_ + chunk * 512 + wid * 128) * 64;
  float* obase = outp + ((size_t)bh * N_ + chunk * 512 + wid * 128) * 64;

  const float* q0 = qbase + (size_t)c * 64 + g * 8;
  f32x4 xp0 = *(const f32x4*)(q0);
  f32x4 xp1 = *(const f32x4*)(q0 + 4);
  f32x4 xp2 = *(const f32x4*)(q0 + 32);
  f32x4 xp3 = *(const f32x4*)(q0 + 36);

#pragma unroll
  for (int rep = 0; rep < 8; ++rep) {
    int e = rep * 2048 + t * 8;
    {
      int row = e >> 6, slot = (e & 63) >> 3;
      short8 v = *(const short8*)(projb + e);
      *(short8*)((char*)sP + row * 128 + ((slot ^ (row & 7)) << 4)) = v;
    }
    {
      int row = e >> 8, slot = (e & 255) >> 3;
      short8 v = *(const short8*)(csrc + e);
      *(short8*)((char*)sC + row * 512 + ((slot ^ (row & 7)) << 4)) = v;
    }
  }
#pragma unroll
  for (int rep = 0; rep < 2; ++rep) {
    int e = rep * 2048 + t * 8;
    int row = e >> 8, col = e & 255, slot = col >> 3;
    short8 v = {0, 0, 0, 0, 0, 0, 0, 0};
    if (row == 0) v = *(const short8*)(khib + col);
    if (row == 1) v = *(const short8*)(klob + col);
    *(short8*)((char*)sC2 + row * 512 + ((slot ^ (row & 7)) << 4)) = v;
  }
  __syncthreads();  // once per block — staging visible

  const int gsw = (g ^ (c & 3)) << 4;
  const int b6 = (c >> 2) & 1;
  const int pb0 = c * 128 + (b6 << 6) + gsw;
  const int pb1 = c * 128 + ((1 ^ b6) << 6) + gsw;
  const char* spc = (const char*)sP;
  const char* scc = (const char*)sC + c * 512;
  const char* sc2c = (const char*)sC2 + c * 512;

#pragma unroll 1
  for (int tt = 0; tt < 8; ++tt) {
    f32x4 x0 = xp0, x1 = xp1, x2 = xp2, x3 = xp3;
    if (tt + 1 < 8) {
      const float* qn = qbase + ((size_t)((tt + 1) * 16 + c)) * 64 + g * 8;
      xp0 = *(const f32x4*)(qn);
      xp1 = *(const f32x4*)(qn + 4);
      xp2 = *(const f32x4*)(qn + 32);
      xp3 = *(const f32x4*)(qn + 36);
    }
    float ss = x0[0]*x0[0] + x0[1]*x0[1] + x0[2]*x0[2] + x0[3]*x0[3]
             + x1[0]*x1[0] + x1[1]*x1[1] + x1[2]*x1[2] + x1[3]*x1[3]
             + x2[0]*x2[0] + x2[1]*x2[1] + x2[2]*x2[2] + x2[3]*x2[3]
             + x3[0]*x3[0] + x3[1]*x3[1] + x3[2]*x3[2] + x3[3]*x3[3];
    ss += __shfl_xor(ss, 16);
    ss += __shfl_xor(ss, 32);
    const float diag = DIAGL * ss;

    short8 xb0, xb1;
#pragma unroll
    for (int j = 0; j < 4; ++j) {
      xb0[j] = (short)f2bf(x0[j]);
      xb0[j + 4] = (short)f2bf(x1[j]);
      xb1[j] = (short)f2bf(x2[j]);
      xb1[j + 4] = (short)f2bf(x3[j]);
    }

    f32x4 acc1[16];
#pragma unroll
    for (int mt = 0; mt < 16; ++mt) acc1[mt] = (f32x4){0.f, 0.f, 0.f, 0.f};
    short8 Ak0[4], Ak1[4], Bk0[4], Bk1[4];
#pragma unroll
    for (int i = 0; i < 4; ++i) {
      Ak0[i] = *(const short8*)(spc + i * 2048 + pb0);
      Ak1[i] = *(const short8*)(spc + i * 2048 + pb1);
    }
#pragma unroll
    for (int i = 0; i < 4; ++i) {
      Bk0[i] = *(const short8*)(spc + (4 + i) * 2048 + pb0);
      Bk1[i] = *(const short8*)(spc + (4 + i) * 2048 + pb1);
    }
#pragma unroll
    for (int i = 0; i < 4; ++i) {
      acc1[i] = __builtin_amdgcn_mfma_f32_16x16x32_bf16(Ak0[i], xb0, acc1[i], 0, 0, 0);
      acc1[i] = __builtin_amdgcn_mfma_f32_16x16x32_bf16(Ak1[i], xb1, acc1[i], 0, 0, 0);
    }
#pragma unroll
    for (int i = 0; i < 4; ++i) {
      Ak0[i] = *(const short8*)(spc + (8 + i) * 2048 + pb0);
      Ak1[i] = *(const short8*)(spc + (8 + i) * 2048 + pb1);
    }
#pragma unroll
    for (int i = 0; i < 4; ++i) {
      acc1[4 + i] = __builtin_amdgcn_mfma_f32_16x16x32_bf16(Bk0[i], xb0, acc1[4 + i], 0, 0, 0);
      acc1[4 + i] = __builtin_amdgcn_mfma_f32_16x16x32_bf16(Bk1[i], xb1, acc1[4 + i], 0, 0, 0);
    }
#pragma unroll
    for (int i = 0; i < 4; ++i) {
      Bk0[i] = *(const short8*)(spc + (12 + i) * 2048 + pb0);
      Bk1[i] = *(const short8*)(spc + (12 + i) * 2048 + pb1);
    }
#pragma unroll
    for (int i = 0; i < 4; ++i) {
      acc1[8 + i] = __builtin_amdgcn_mfma_f32_16x16x32_bf16(Ak0[i], xb0, acc1[8 + i], 0, 0, 0);
      acc1[8 + i] = __builtin_amdgcn_mfma_f32_16x16x32_bf16(Ak1[i], xb1, acc1[8 + i], 0, 0, 0);
    }
#pragma unroll
    for (int i = 0; i < 4; ++i) {
      acc1[12 + i] = __builtin_amdgcn_mfma_f32_16x16x32_bf16(Bk0[i], xb0, acc1[12 + i], 0, 0, 0);
      acc1[12 + i] = __builtin_amdgcn_mfma_f32_16x16x32_bf16(Bk1[i], xb1, acc1[12 + i], 0, 0, 0);
    }

    float mx = acc1[0][0];
#pragma unroll
    for (int mt = 0; mt < 16; ++mt)
#pragma unroll
      for (int r = 0; r < 4; ++r) mx = fmaxf(mx, acc1[mt][r]);
    mx = fmaxf(mx, __shfl_xor(mx, 16));
    mx = fmaxf(mx, __shfl_xor(mx, 32));
    const float base = diag + mx;

    uint2 qtp[16];
#pragma unroll
    for (int mt = 0; mt < 16; ++mt) {
      float qa = EXP2F(acc1[mt][0] - base) + EPSF;
      float qb = EXP2F(acc1[mt][1] - base) + EPSF;
      float qc = EXP2F(acc1[mt][2] - base) + EPSF;
      float qd = EXP2F(acc1[mt][3] - base) + EPSF;
      qtp[mt].x = pk2bf(qa, qb);
      qtp[mt].y = pk2bf(qc, qd);
    }

    f32x4 acc2[5];
#pragma unroll
    for (int et = 0; et < 5; ++et) acc2[et] = (f32x4){0.f, 0.f, 0.f, 0.f};
#pragma unroll
    for (int w = 0; w < 8; ++w) {
      const int colb = ((w ^ b6) << 6) + gsw;
      short8 b0 = *(const short8*)(scc + colb);
      short8 b1 = *(const short8*)(scc + colb + 8192);
      short8 b2 = *(const short8*)(scc + colb + 16384);
      short8 b3 = *(const short8*)(scc + colb + 24576);
      short8 bd = *(const short8*)(sc2c + colb);
      u32x4 av = {qtp[2 * w].x, qtp[2 * w].y, qtp[2 * w + 1].x, qtp[2 * w + 1].y};
      short8 a = __builtin_bit_cast(short8, av);
      acc2[0] = __builtin_amdgcn_mfma_f32_16x16x32_bf16(a, b0, acc2[0], 0, 0, 0);
      acc2[1] = __builtin_amdgcn_mfma_f32_16x16x32_bf16(a, b1, acc2[1], 0, 0, 0);
      acc2[2] = __builtin_amdgcn_mfma_f32_16x16x32_bf16(a, b2, acc2[2], 0, 0, 0);
      acc2[3] = __builtin_amdgcn_mfma_f32_16x16x32_bf16(a, b3, acc2[3], 0, 0, 0);
      acc2[4] = __builtin_amdgcn_mfma_f32_16x16x32_bf16(a, bd, acc2[4], 0, 0, 0);
    }

    float* ot = obase + (size_t)tt * 16 * 64;
#pragma unroll
    for (int r = 0; r < 4; ++r) {
      float den = __shfl(acc2[4][r], g * 16) + __shfl(acc2[4][r], g * 16 + 1);
      float rinv = 1.0f / den;
      int n = g * 4 + r;
#pragma unroll
      for (int et = 0; et < 4; ++et)
        ot[(size_t)n * 64 + et * 16 + c] = acc2[et][r] * rinv;
    }
  }
}

extern "C" void kernel_launch(void* const* d_in, const int* in_sizes, int n_in,
                              void* d_out, int out_size, void* d_ws, size_t ws_size,
                              hipStream_t stream) {
  (void)in_sizes; (void)n_in; (void)out_size;
  const float* qp = (const float*)d_in[0];
  const float* kp = (const float*)d_in[1];
  const float* vp = (const float*)d_in[2];
  const float* proj = (const float*)d_in[3];
  float* outp = (float*)d_out;

  int nchunk = 8;
  while (nchunk > 1) {
    size_t fl = 64 + (size_t)nchunk * (2097152 + 32768 + 8192);
    size_t needed = fl * 4 + (size_t)(2097152 + 32768 + 32768 + 16384) * 2;
    if (needed <= ws_size) break;
    nchunk >>= 1;
  }

  float* wsf = (float*)d_ws;
  unsigned int* gmaxb = (unsigned int*)d_ws;
  float* ctxp = wsf + 64;
  float* kexpp = ctxp + (size_t)nchunk * 128 * 64 * 256;
  float* vsump = kexpp + (size_t)nchunk * 128 * 256;
  unsigned short* ctxt = (unsigned short*)(vsump + (size_t)nchunk * 128 * 64);
  unsigned short* kchi = ctxt + (size_t)128 * 64 * 256;
  unsigned short* kclo = kchi + 128 * 256;
  unsigned short* projb = kclo + 128 * 256;

  hipMemsetAsync(d_ws, 0, 16, stream);
  hipLaunchKernelGGL(perf_prep, dim3(64), dim3(256), 0, stream, proj, projb);
  hipLaunchKernelGGL(perf_kpass, dim3(128 * nchunk), dim3(256), 0, stream,
                     kp, vp, proj, ctxp, kexpp, vsump, gmaxb, nchunk);
  hipLaunchKernelGGL(perf_rescale, dim3(128 * 8), dim3(256), 0, stream,
                     ctxp, kexpp, vsump, ctxt, kchi, kclo, gmaxb, nchunk);
  hipLaunchKernelGGL(perf_qpass, dim3(128 * 8), dim3(256), 0, stream,
                     qp, projb, ctxt, kchi, kclo, outp);
}